// Round 5
// baseline (1190.299 us; speedup 1.0000x reference)
//
#include <hip/hip_runtime.h>
#include <stdint.h>

// L=512, B=32, D=H=256
// Workspace (float offsets into 64MB d_ws):
//   Eq  f16[16384*256] @ 0
//   Ev  f16[16384*256] @ 2097152
//   VT  f16[32][256][512] @ 4194304
//   S   f32[32*512*512] @ 6291456   (raw scores; softmax fused into ctxsm_k)
//   C   f32[16384*256] @ 0          (reuse Eq+Ev, dead after score)
//   Gi2 f16[16384*768] @ 6291456    (reuse S, dead after ctxsm)

#define C2    2.8853900817779268f   // 2*log2(e)
#define LOG2E 1.4426950408889634f

typedef __fp16 f16x2 __attribute__((ext_vector_type(2)));
typedef __fp16 f16x4_t __attribute__((ext_vector_type(4)));
typedef __fp16 f16x8 __attribute__((ext_vector_type(8)));
typedef float f32x4 __attribute__((ext_vector_type(4)));

static __device__ __forceinline__ float rcp_f(float x)  { return __builtin_amdgcn_rcpf(x); }
static __device__ __forceinline__ float exp2_f(float x) { return __builtin_amdgcn_exp2f(x); }
#if __has_builtin(__builtin_amdgcn_rcph)
static __device__ __forceinline__ __fp16 rcph(__fp16 x) {
  return (__fp16)__builtin_amdgcn_rcph((_Float16)x);
}
#else
static __device__ __forceinline__ __fp16 rcph(__fp16 x) {
  return (__fp16)__builtin_amdgcn_rcpf((float)x);
}
#endif
static __device__ __forceinline__ float dot2f(f16x2 a, f16x2 b, float c) {
  return __builtin_amdgcn_fdot2(a, b, c, false);
}
static __device__ __forceinline__ f16x8 cvt8(float4 a, float4 b) {
  f16x8 f;
  f[0] = (__fp16)a.x; f[1] = (__fp16)a.y; f[2] = (__fp16)a.z; f[3] = (__fp16)a.w;
  f[4] = (__fp16)b.x; f[5] = (__fp16)b.y; f[6] = (__fp16)b.z; f[7] = (__fp16)b.w;
  return f;
}

// Fragment conventions (verified end-to-end):
//   A-frag: lane(col=lane&15, quad=lane>>4) holds A[m=col][k=quad*8+jj]
//   B-frag: lane holds B[k=quad*8+jj][n=col]
//   C/D:    row(m)=quad*4+reg, col(n)=lane&15

// ---------------------------------------------------------------------------
// Fused projections -> f16 with exponent clamp to f16-normal range.
// ---------------------------------------------------------------------------
__global__ __launch_bounds__(256) void proj_k(
    const float* __restrict__ v, const float* __restrict__ Wp,
    const float* __restrict__ Wp_, __fp16* __restrict__ Eq,
    __fp16* __restrict__ Ev)
{
  __shared__ __align__(16) __fp16 As[64][40];
  __shared__ __align__(16) __fp16 Wqs[64][40];
  __shared__ __align__(16) __fp16 Wvs[64][40];
  const int t = threadIdx.x, wave = t >> 6, lane = t & 63;
  const int quad = lane >> 4, col = lane & 15;
  const int n0 = blockIdx.x * 64, m0 = blockIdx.y * 64;
  const int srow = t >> 2, skq = t & 3;

  f32x4 accq[4], accv[4];
#pragma unroll
  for (int nt = 0; nt < 4; ++nt) {
    accq[nt] = (f32x4){0.f, 0.f, 0.f, 0.f};
    accv[nt] = (f32x4){0.f, 0.f, 0.f, 0.f};
  }

  for (int kc = 0; kc < 8; ++kc) {
    const int k0 = kc * 32;
    {
      const float4* ap = (const float4*)&v[(size_t)(m0 + srow) * 256 + k0 + skq * 8];
      *(f16x8*)&As[srow][skq * 8] = cvt8(ap[0], ap[1]);
      const float4* qp = (const float4*)&Wp[(size_t)(n0 + srow) * 256 + k0 + skq * 8];
      *(f16x8*)&Wqs[srow][skq * 8] = cvt8(qp[0], qp[1]);
      const float4* vp = (const float4*)&Wp_[(size_t)(n0 + srow) * 256 + k0 + skq * 8];
      *(f16x8*)&Wvs[srow][skq * 8] = cvt8(vp[0], vp[1]);
    }
    __syncthreads();
    f16x8 a = *(const f16x8*)&As[wave * 16 + col][quad * 8];
#pragma unroll
    for (int nt = 0; nt < 4; ++nt) {
      f16x8 bq = *(const f16x8*)&Wqs[nt * 16 + col][quad * 8];
      f16x8 bv = *(const f16x8*)&Wvs[nt * 16 + col][quad * 8];
      accq[nt] = __builtin_amdgcn_mfma_f32_16x16x32_f16(a, bq, accq[nt], 0, 0, 0);
      accv[nt] = __builtin_amdgcn_mfma_f32_16x16x32_f16(a, bv, accv[nt], 0, 0, 0);
    }
    __syncthreads();
  }

#pragma unroll
  for (int nt = 0; nt < 4; ++nt)
#pragma unroll
    for (int r = 0; r < 4; ++r) {
      size_t m = m0 + wave * 16 + quad * 4 + r;
      size_t n = n0 + nt * 16 + col;
      float eq = C2 * accq[nt][r], ev = C2 * accv[nt][r];
      eq = fminf(fmaxf(eq, -14.f), 15.5f);
      ev = fminf(fmaxf(ev, -14.f), 15.5f);
      Eq[m * 256 + n] = (__fp16)exp2_f(eq);
      Ev[m * 256 + n] = (__fp16)exp2_f(ev);
    }
}

// ---------------------------------------------------------------------------
// v transpose: VT[b][d][l] (f16) from v[l][b][d] (f32). 32x32 LDS tiles.
// ---------------------------------------------------------------------------
__global__ __launch_bounds__(256) void vt_k(
    const float* __restrict__ v, __fp16* __restrict__ VT)
{
  __shared__ float Ts[32][33];
  const int t = threadIdx.x;
  const int d0 = blockIdx.x * 32, l0 = blockIdx.y * 32, b = blockIdx.z;
  {
    int lrow = t >> 3, dq = t & 7;
    float4 a = *(const float4*)&v[((size_t)(l0 + lrow) * 32 + b) * 256 + d0 + dq * 4];
    Ts[dq * 4 + 0][lrow] = a.x; Ts[dq * 4 + 1][lrow] = a.y;
    Ts[dq * 4 + 2][lrow] = a.z; Ts[dq * 4 + 3][lrow] = a.w;
  }
  __syncthreads();
  {
    int drow = t >> 3, lq = t & 7;
    f16x4_t o;
#pragma unroll
    for (int e = 0; e < 4; ++e) o[e] = (__fp16)Ts[drow][lq * 4 + e];
    *(f16x4_t*)&VT[((size_t)b * 256 + d0 + drow) * 512 + l0 + lq * 4] = o;
  }
}

// ---------------------------------------------------------------------------
// Packed-f16 score: S[b][i][l] = -2 * sum_h V[b][h] * rcp(1 + Eq*Ev).
// ---------------------------------------------------------------------------
__global__ __launch_bounds__(256) void score_k(
    const __fp16* __restrict__ Eq, const __fp16* __restrict__ Ev,
    const float* __restrict__ Vvec, float* __restrict__ S)
{
  __shared__ __align__(16) __fp16 Eqs[64][72];
  __shared__ __align__(16) __fp16 Evs[32][72];
  __shared__ __align__(16) __fp16 Vs[256];
  const int t = threadIdx.x;
  const int tx = t & 15, ty = t >> 4;
  const int l0 = blockIdx.x * 32;
  const int i0 = blockIdx.y * 64;
  const int b  = blockIdx.z;

  Vs[t] = (__fp16)(-2.0f * Vvec[b * 256 + t]);
  float acc[4][2] = {};
  const f16x2 one2 = {(__fp16)1.f, (__fp16)1.f};

  for (int st = 0; st < 4; ++st) {
    const int h0 = st * 64;
#pragma unroll
    for (int s = 0; s < 2; ++s) {
      int f = t + s * 256;
      int row = f >> 3, cq = f & 7;
      *(f16x8*)&Eqs[row][cq * 8] =
          *(const f16x8*)&Eq[((size_t)(i0 + row) * 32 + b) * 256 + h0 + cq * 8];
    }
    {
      int row = t >> 3, cq = t & 7;
      *(f16x8*)&Evs[row][cq * 8] =
          *(const f16x8*)&Ev[((size_t)(l0 + row) * 32 + b) * 256 + h0 + cq * 8];
    }
    __syncthreads();

#pragma unroll
    for (int k8 = 0; k8 < 8; ++k8) {
      f16x8 vh8 = *(const f16x8*)&Vs[h0 + k8 * 8];
      f16x8 ev80 = *(const f16x8*)&Evs[tx][k8 * 8];
      f16x8 ev81 = *(const f16x8*)&Evs[tx + 16][k8 * 8];
      f16x8 eq8[4];
#pragma unroll
      for (int r = 0; r < 4; ++r)
        eq8[r] = *(const f16x8*)&Eqs[ty * 4 + r][k8 * 8];
#pragma unroll
      for (int q = 0; q < 4; ++q) {
        f16x2 vh2 = {vh8[q * 2], vh8[q * 2 + 1]};
        f16x2 e0  = {ev80[q * 2], ev80[q * 2 + 1]};
        f16x2 e1  = {ev81[q * 2], ev81[q * 2 + 1]};
#pragma unroll
        for (int r = 0; r < 4; ++r) {
          f16x2 eq2 = {eq8[r][q * 2], eq8[r][q * 2 + 1]};
          f16x2 d0 = eq2 * e0 + one2;   // v_pk_fma_f16
          f16x2 d1 = eq2 * e1 + one2;
          f16x2 r0 = {rcph(d0[0]), rcph(d0[1])};
          f16x2 r1 = {rcph(d1[0]), rcph(d1[1])};
          acc[r][0] = dot2f(vh2, r0, acc[r][0]);
          acc[r][1] = dot2f(vh2, r1, acc[r][1]);
        }
      }
    }
    __syncthreads();
  }

#pragma unroll
  for (int r = 0; r < 4; ++r) {
    float* ps = &S[((size_t)b * 512 + i0 + ty * 4 + r) * 512 + l0];
    ps[tx]      = acc[r][0];
    ps[tx + 16] = acc[r][1];
  }
}

// ---------------------------------------------------------------------------
// FUSED softmax + context: C[i][b][d] = sum_l softmax_l(S[b][i][:])[l] * VT[b][d][l].
// ---------------------------------------------------------------------------
__global__ __launch_bounds__(512) void ctxsm_k(
    const float* __restrict__ S, const __fp16* __restrict__ VT,
    float* __restrict__ C)
{
  __shared__ __align__(16) __fp16 As[64][40];
  __shared__ __align__(16) __fp16 Vs[256][40];
  __shared__ float red[64][8];
  __shared__ float stat_m[64], stat_inv[64];
  const int t = threadIdx.x, wave = t >> 6, lane = t & 63;
  const int quad = lane >> 4, col = lane & 15;
  const int i0 = blockIdx.x * 64, b = blockIdx.y;
  const int mt = wave & 3, nh = wave >> 2;

  // ---- phase 1: row stats ----
  {
    const int row = t >> 3, seg = t & 7;
    const float* sp = &S[((size_t)b * 512 + i0 + row) * 512 + seg * 64];
    float m = -1e30f;
#pragma unroll
    for (int u = 0; u < 16; ++u) {
      float4 x = *(const float4*)&sp[u * 4];
      m = fmaxf(m, fmaxf(fmaxf(x.x, x.y), fmaxf(x.z, x.w)));
    }
    red[row][seg] = m;
    __syncthreads();
    if (seg == 0) {
      float mm = red[row][0];
#pragma unroll
      for (int u = 1; u < 8; ++u) mm = fmaxf(mm, red[row][u]);
      stat_m[row] = mm;
    }
    __syncthreads();
    float M = stat_m[row];
    float s = 0.f;
#pragma unroll
    for (int u = 0; u < 16; ++u) {
      float4 x = *(const float4*)&sp[u * 4];
      s += exp2_f(LOG2E * (x.x - M)) + exp2_f(LOG2E * (x.y - M)) +
           exp2_f(LOG2E * (x.z - M)) + exp2_f(LOG2E * (x.w - M));
    }
    red[row][seg] = s;
    __syncthreads();
    if (seg == 0) {
      float ss = red[row][0];
#pragma unroll
      for (int u = 1; u < 8; ++u) ss += red[row][u];
      stat_inv[row] = rcp_f(ss);
    }
    __syncthreads();
  }

  // ---- phase 2: MFMA with softmax applied at A staging ----
  f32x4 acc[8];
#pragma unroll
  for (int n = 0; n < 8; ++n) acc[n] = (f32x4){0.f, 0.f, 0.f, 0.f};

  for (int kc = 0; kc < 16; ++kc) {
    const int l0 = kc * 32;
    {
      int arow = t >> 3, aq = t & 7;
      float M = stat_m[arow], inv = stat_inv[arow];
      float4 x = *(const float4*)&S[((size_t)b * 512 + i0 + arow) * 512 + l0 + aq * 4];
      f16x4_t o;
      o[0] = (__fp16)(exp2_f(LOG2E * (x.x - M)) * inv);
      o[1] = (__fp16)(exp2_f(LOG2E * (x.y - M)) * inv);
      o[2] = (__fp16)(exp2_f(LOG2E * (x.z - M)) * inv);
      o[3] = (__fp16)(exp2_f(LOG2E * (x.w - M)) * inv);
      *(f16x4_t*)&As[arow][aq * 4] = o;
#pragma unroll
      for (int s2 = 0; s2 < 2; ++s2) {
        int f = t + s2 * 512;
        int vrow = f >> 2, vq = f & 3;
        *(f16x8*)&Vs[vrow][vq * 8] =
            *(const f16x8*)&VT[((size_t)b * 256 + vrow) * 512 + l0 + vq * 8];
      }
    }
    __syncthreads();
    f16x8 a = *(const f16x8*)&As[mt * 16 + col][quad * 8];
#pragma unroll
    for (int n = 0; n < 8; ++n) {
      f16x8 vf = *(const f16x8*)&Vs[nh * 128 + n * 16 + col][quad * 8];
      acc[n] = __builtin_amdgcn_mfma_f32_16x16x32_f16(a, vf, acc[n], 0, 0, 0);
    }
    __syncthreads();
  }

#pragma unroll
  for (int n = 0; n < 8; ++n)
#pragma unroll
    for (int r = 0; r < 4; ++r) {
      size_t i = i0 + mt * 16 + quad * 4 + r;
      size_t d = nh * 128 + n * 16 + col;
      C[(i * 32 + b) * 256 + d] = acc[n][r];
    }
}

// ---------------------------------------------------------------------------
// Gi2 = f16( C @ Wih^T + bih (+bhh for gates r,z) ). M=16384, N=768, K=256.
// ---------------------------------------------------------------------------
__global__ __launch_bounds__(256) void gi_k(
    const float* __restrict__ A, const float* __restrict__ W,
    const float* __restrict__ bih, const float* __restrict__ bhh,
    __fp16* __restrict__ G)
{
  __shared__ __align__(16) __fp16 As[64][40];
  __shared__ __align__(16) __fp16 Ws[64][40];
  const int t = threadIdx.x, wave = t >> 6, lane = t & 63;
  const int quad = lane >> 4, col = lane & 15;
  const int n0 = blockIdx.x * 64, m0 = blockIdx.y * 64;
  const int srow = t >> 2, skq = t & 3;

  f32x4 acc[4];
#pragma unroll
  for (int nt = 0; nt < 4; ++nt) acc[nt] = (f32x4){0.f, 0.f, 0.f, 0.f};

  for (int kc = 0; kc < 8; ++kc) {
    const int k0 = kc * 32;
    {
      const float4* ap = (const float4*)&A[(size_t)(m0 + srow) * 256 + k0 + skq * 8];
      *(f16x8*)&As[srow][skq * 8] = cvt8(ap[0], ap[1]);
      const float4* wp = (const float4*)&W[(size_t)(n0 + srow) * 256 + k0 + skq * 8];
      *(f16x8*)&Ws[srow][skq * 8] = cvt8(wp[0], wp[1]);
    }
    __syncthreads();
    f16x8 a = *(const f16x8*)&As[wave * 16 + col][quad * 8];
#pragma unroll
    for (int nt = 0; nt < 4; ++nt) {
      f16x8 b = *(const f16x8*)&Ws[nt * 16 + col][quad * 8];
      acc[nt] = __builtin_amdgcn_mfma_f32_16x16x32_f16(a, b, acc[nt], 0, 0, 0);
    }
    __syncthreads();
  }

#pragma unroll
  for (int nt = 0; nt < 4; ++nt) {
    int n = n0 + nt * 16 + col;
    float bias = bih[n] + (n < 512 ? bhh[n] : 0.f);
#pragma unroll
    for (int r = 0; r < 4; ++r) {
      size_t m = m0 + wave * 16 + quad * 4 + r;
      G[m * 768 + n] = (__fp16)(acc[nt][r] + bias);
    }
  }
}

// ---------------------------------------------------------------------------
// R4 = R3 resubmitted (R3 bench was an infra failure: container acquisition
// died twice; no pytest/profile data. Kernel re-audited: uniform barriers,
// VGPR budget <256 at 2 waves/SIMD, OOB-safe dead prefetch.)
//
// VALU-dot2 GRU. MFMA matvec wasted 16x (broadcast A rows): MFMA pipe
// floor 1862 cyc/iter (measured 64% of active-CU peak). v_dot2_f32_f16 at
// full VALU rate gives 2.4x better useful throughput for matvec:
//   h-lane (t<256, j=t):    holds Whh_r[j][0:256] + Whh_n[j][0:128] as f16x2
//   z-lane (t>=256, j=t-256): holds Whh_z[j][0:256] + Whh_n[j][128:256]
// 192 dot2 per lane per step (perfectly balanced). h broadcast via LDS with
// wave-uniform ds_read_b128 (free broadcast). z-lane ships {zz, pn_high} to
// h-lane through LDS (barrier A); h-lane finishes gates, writes h (barrier B).
// Numerics identical to MFMA path (f16 inputs, f32 accumulation).
// ---------------------------------------------------------------------------
__global__ __launch_bounds__(512, 1) void gru_k(
    const __fp16* __restrict__ Gi2, const float* __restrict__ Whh,
    const float* __restrict__ bhh, const float* __restrict__ h0,
    float* __restrict__ out)
{
  __shared__ __align__(16) __fp16 hA[2][256];
  __shared__ __align__(16) float xbuf[256][2];   // {zz, pn_high} per j
  const int t = threadIdx.x;
  const bool hlane = t < 256;
  const int j = hlane ? t : (t - 256);
  const int b = blockIdx.x;

  // ---- stage weight rows into registers as f16x2 (static indices only) ----
  f16x2 Wr_[128];  // primary row: Whh_r[j][:] (hlane) / Whh_z[j][:] (zlane)
  f16x2 Wn_[64];   // n-gate half: k in [0,128) (hlane) / [128,256) (zlane)
  {
    const float* prow = &Whh[(size_t)((hlane ? 0 : 256) + j) * 256];
    const float* nrow = &Whh[(size_t)(512 + j) * 256 + (hlane ? 0 : 128)];
#pragma unroll
    for (int u = 0; u < 64; ++u) {
      float4 x = *(const float4*)&prow[u * 4];
      Wr_[u * 2 + 0] = (f16x2){(__fp16)x.x, (__fp16)x.y};
      Wr_[u * 2 + 1] = (f16x2){(__fp16)x.z, (__fp16)x.w};
    }
#pragma unroll
    for (int u = 0; u < 32; ++u) {
      float4 x = *(const float4*)&nrow[u * 4];
      Wn_[u * 2 + 0] = (f16x2){(__fp16)x.x, (__fp16)x.y};
      Wn_[u * 2 + 1] = (f16x2){(__fp16)x.z, (__fp16)x.w};
    }
  }

  float hold = 0.f, bn = 0.f;
  if (hlane) {
    hold = h0[(size_t)b * 256 + j];
    bn = bhh[512 + j];
    hA[0][j] = (__fp16)hold;
  }
  __syncthreads();

  // Gi2: layout G[(i*32+b)*768 + g*256 + j]; row stride 24576 halfs.
  // h-lane needs g=0 (r) and g=2 (n); z-lane needs g=1 (z).
  const __fp16* gp = &Gi2[(size_t)b * 768 + (hlane ? j : 256 + j)];
  float g0 = (float)gp[0];                       // gi_r (hlane) / gi_z (zlane)
  float g1 = hlane ? (float)gp[512] : 0.f;       // gi_n (hlane only)
  const __fp16* gq = gp + 24576;                 // row i=1

  float* outp = &out[(size_t)b * 256 + j];

  for (int i = 0; i < 512; ++i) {
    // prefetch next Gi2 row; cvt to f32 off the critical path
    float n0f = (float)gq[0];
    float n1f = hlane ? (float)gq[512] : 0.f;
    gq += 24576;

    // ---- dot phase: stream h (wave-uniform LDS reads, broadcast) ----
    const __fp16* hbuf = hA[i & 1];
    float pa0 = 0.f, pa1 = 0.f, pa2 = 0.f, pa3 = 0.f;  // primary gate
    float pn0 = 0.f, pn1 = 0.f;                        // n-gate half
    if (hlane) {
#pragma unroll
      for (int c = 0; c < 32; ++c) {
        f16x8 hc = *(const f16x8*)&hbuf[c * 8];
        f16x2 h0c = __builtin_shufflevector(hc, hc, 0, 1);
        f16x2 h1c = __builtin_shufflevector(hc, hc, 2, 3);
        f16x2 h2c = __builtin_shufflevector(hc, hc, 4, 5);
        f16x2 h3c = __builtin_shufflevector(hc, hc, 6, 7);
        pa0 = dot2f(h0c, Wr_[c * 4 + 0], pa0);
        pa1 = dot2f(h1c, Wr_[c * 4 + 1], pa1);
        pa2 = dot2f(h2c, Wr_[c * 4 + 2], pa2);
        pa3 = dot2f(h3c, Wr_[c * 4 + 3], pa3);
        if (c < 16) {  // n-gate low half: k in [0,128)
          pn0 = dot2f(h0c, Wn_[c * 4 + 0], pn0);
          pn1 = dot2f(h1c, Wn_[c * 4 + 1], pn1);
          pn0 = dot2f(h2c, Wn_[c * 4 + 2], pn0);
          pn1 = dot2f(h3c, Wn_[c * 4 + 3], pn1);
        }
      }
    } else {
#pragma unroll
      for (int c = 0; c < 32; ++c) {
        f16x8 hc = *(const f16x8*)&hbuf[c * 8];
        f16x2 h0c = __builtin_shufflevector(hc, hc, 0, 1);
        f16x2 h1c = __builtin_shufflevector(hc, hc, 2, 3);
        f16x2 h2c = __builtin_shufflevector(hc, hc, 4, 5);
        f16x2 h3c = __builtin_shufflevector(hc, hc, 6, 7);
        pa0 = dot2f(h0c, Wr_[c * 4 + 0], pa0);
        pa1 = dot2f(h1c, Wr_[c * 4 + 1], pa1);
        pa2 = dot2f(h2c, Wr_[c * 4 + 2], pa2);
        pa3 = dot2f(h3c, Wr_[c * 4 + 3], pa3);
        if (c >= 16) {  // n-gate high half: k in [128,256)
          pn0 = dot2f(h0c, Wn_[(c - 16) * 4 + 0], pn0);
          pn1 = dot2f(h1c, Wn_[(c - 16) * 4 + 1], pn1);
          pn0 = dot2f(h2c, Wn_[(c - 16) * 4 + 2], pn0);
          pn1 = dot2f(h3c, Wn_[(c - 16) * 4 + 3], pn1);
        }
      }
    }
    float ghp = (pa0 + pa1) + (pa2 + pa3);
    float pn  = pn0 + pn1;
    // primary sigmoid: rr (hlane) / zz (zlane)
    float sig = rcp_f(1.f + exp2_f(-LOG2E * (g0 + ghp)));
    if (!hlane) {
      xbuf[j][0] = sig;
      xbuf[j][1] = pn;
    }
    // barrier A: zz/pn_high handoff (lgkm-only drain, proven R2 pattern)
    asm volatile("s_waitcnt lgkmcnt(0)" ::: "memory");
    __builtin_amdgcn_s_barrier();
    asm volatile("" ::: "memory");
    if (hlane) {
      float zz  = xbuf[j][0];
      float pnz = xbuf[j][1];
      float ghn = (pn + pnz) + bn;
      float na  = fmaf(sig, ghn, g1);                       // gi_n + rr*ghn
      float nn  = fmaf(-2.f, rcp_f(1.f + exp2_f(C2 * na)), 1.f);
      float h   = fmaf(zz, hold - nn, nn);
      hold = h;
      outp[0] = h;
      hA[(i + 1) & 1][j] = (__fp16)h;
    }
    outp += 8192;
    g0 = n0f; g1 = n1f;
    // barrier B: h handoff for next iteration
    asm volatile("s_waitcnt lgkmcnt(0)" ::: "memory");
    __builtin_amdgcn_s_barrier();
    asm volatile("" ::: "memory");
  }
}

// ---------------------------------------------------------------------------
extern "C" void kernel_launch(void* const* d_in, const int* in_sizes, int n_in,
                              void* d_out, int out_size, void* d_ws, size_t ws_size,
                              hipStream_t stream)
{
  const float* v   = (const float*)d_in[0];
  const float* h0  = (const float*)d_in[1];
  const float* Vv  = (const float*)d_in[2];
  const float* Wp  = (const float*)d_in[3];
  const float* Wp_ = (const float*)d_in[4];
  const float* Wih = (const float*)d_in[5];
  const float* Whh = (const float*)d_in[6];
  const float* bih = (const float*)d_in[7];
  const float* bhh = (const float*)d_in[8];
  float* out = (float*)d_out;
  float* ws  = (float*)d_ws;

  __fp16* Eq  = (__fp16*)ws;
  __fp16* Ev  = (__fp16*)(ws + 2097152);
  __fp16* VT  = (__fp16*)(ws + 4194304);
  float*  S   = ws + 6291456;
  float*  C   = ws;                        // reuse Eq+Ev (dead after score)
  __fp16* Gi2 = (__fp16*)(ws + 6291456);   // reuse S (dead after ctxsm)

  proj_k<<<dim3(4, 256), 256, 0, stream>>>(v, Wp, Wp_, Eq, Ev);
  vt_k<<<dim3(8, 16, 32), 256, 0, stream>>>(v, VT);
  score_k<<<dim3(16, 8, 32), 256, 0, stream>>>(Eq, Ev, Vv, S);
  ctxsm_k<<<dim3(8, 32), 512, 0, stream>>>(S, VT, C);
  gi_k<<<dim3(12, 256), 256, 0, stream>>>(C, Wih, bih, bhh, Gi2);
  gru_k<<<32, 512, 0, stream>>>(Gi2, Whh, bhh, h0, out);
}

// Round 6
// 1042.150 us; speedup vs baseline: 1.1422x; 1.1422x over previous
//
#include <hip/hip_runtime.h>
#include <stdint.h>

// L=512, B=32, D=H=256
// Workspace (float offsets into 64MB d_ws):
//   Eq  f16[16384*256] @ 0
//   Ev  f16[16384*256] @ 2097152
//   VT  f16[32][256][512] @ 4194304
//   S   f32[32*512*512] @ 6291456   (raw scores; softmax fused into ctxsm_k)
//   C   f32[16384*256] @ 0          (reuse Eq+Ev, dead after score)
//   Gi2 f16[16384*768] @ 6291456    (reuse S, dead after ctxsm)

#define C2    2.8853900817779268f   // 2*log2(e)
#define LOG2E 1.4426950408889634f

typedef __fp16 f16x2 __attribute__((ext_vector_type(2)));
typedef __fp16 f16x4_t __attribute__((ext_vector_type(4)));
typedef __fp16 f16x8 __attribute__((ext_vector_type(8)));
typedef float f32x4 __attribute__((ext_vector_type(4)));

static __device__ __forceinline__ float rcp_f(float x)  { return __builtin_amdgcn_rcpf(x); }
static __device__ __forceinline__ float exp2_f(float x) { return __builtin_amdgcn_exp2f(x); }
#if __has_builtin(__builtin_amdgcn_rcph)
static __device__ __forceinline__ __fp16 rcph(__fp16 x) {
  return (__fp16)__builtin_amdgcn_rcph((_Float16)x);
}
#else
static __device__ __forceinline__ __fp16 rcph(__fp16 x) {
  return (__fp16)__builtin_amdgcn_rcpf((float)x);
}
#endif
static __device__ __forceinline__ float dot2f(f16x2 a, f16x2 b, float c) {
  return __builtin_amdgcn_fdot2(a, b, c, false);
}
static __device__ __forceinline__ f16x8 cvt8(float4 a, float4 b) {
  f16x8 f;
  f[0] = (__fp16)a.x; f[1] = (__fp16)a.y; f[2] = (__fp16)a.z; f[3] = (__fp16)a.w;
  f[4] = (__fp16)b.x; f[5] = (__fp16)b.y; f[6] = (__fp16)b.z; f[7] = (__fp16)b.w;
  return f;
}

// Fragment conventions (verified end-to-end):
//   A-frag: lane(col=lane&15, quad=lane>>4) holds A[m=col][k=quad*8+jj]
//   B-frag: lane holds B[k=quad*8+jj][n=col]
//   C/D:    row(m)=quad*4+reg, col(n)=lane&15

// ---------------------------------------------------------------------------
// Fused projections -> f16 with exponent clamp to f16-normal range.
// ---------------------------------------------------------------------------
__global__ __launch_bounds__(256) void proj_k(
    const float* __restrict__ v, const float* __restrict__ Wp,
    const float* __restrict__ Wp_, __fp16* __restrict__ Eq,
    __fp16* __restrict__ Ev)
{
  __shared__ __align__(16) __fp16 As[64][40];
  __shared__ __align__(16) __fp16 Wqs[64][40];
  __shared__ __align__(16) __fp16 Wvs[64][40];
  const int t = threadIdx.x, wave = t >> 6, lane = t & 63;
  const int quad = lane >> 4, col = lane & 15;
  const int n0 = blockIdx.x * 64, m0 = blockIdx.y * 64;
  const int srow = t >> 2, skq = t & 3;

  f32x4 accq[4], accv[4];
#pragma unroll
  for (int nt = 0; nt < 4; ++nt) {
    accq[nt] = (f32x4){0.f, 0.f, 0.f, 0.f};
    accv[nt] = (f32x4){0.f, 0.f, 0.f, 0.f};
  }

  for (int kc = 0; kc < 8; ++kc) {
    const int k0 = kc * 32;
    {
      const float4* ap = (const float4*)&v[(size_t)(m0 + srow) * 256 + k0 + skq * 8];
      *(f16x8*)&As[srow][skq * 8] = cvt8(ap[0], ap[1]);
      const float4* qp = (const float4*)&Wp[(size_t)(n0 + srow) * 256 + k0 + skq * 8];
      *(f16x8*)&Wqs[srow][skq * 8] = cvt8(qp[0], qp[1]);
      const float4* vp = (const float4*)&Wp_[(size_t)(n0 + srow) * 256 + k0 + skq * 8];
      *(f16x8*)&Wvs[srow][skq * 8] = cvt8(vp[0], vp[1]);
    }
    __syncthreads();
    f16x8 a = *(const f16x8*)&As[wave * 16 + col][quad * 8];
#pragma unroll
    for (int nt = 0; nt < 4; ++nt) {
      f16x8 bq = *(const f16x8*)&Wqs[nt * 16 + col][quad * 8];
      f16x8 bv = *(const f16x8*)&Wvs[nt * 16 + col][quad * 8];
      accq[nt] = __builtin_amdgcn_mfma_f32_16x16x32_f16(a, bq, accq[nt], 0, 0, 0);
      accv[nt] = __builtin_amdgcn_mfma_f32_16x16x32_f16(a, bv, accv[nt], 0, 0, 0);
    }
    __syncthreads();
  }

#pragma unroll
  for (int nt = 0; nt < 4; ++nt)
#pragma unroll
    for (int r = 0; r < 4; ++r) {
      size_t m = m0 + wave * 16 + quad * 4 + r;
      size_t n = n0 + nt * 16 + col;
      float eq = C2 * accq[nt][r], ev = C2 * accv[nt][r];
      eq = fminf(fmaxf(eq, -14.f), 15.5f);
      ev = fminf(fmaxf(ev, -14.f), 15.5f);
      Eq[m * 256 + n] = (__fp16)exp2_f(eq);
      Ev[m * 256 + n] = (__fp16)exp2_f(ev);
    }
}

// ---------------------------------------------------------------------------
// v transpose: VT[b][d][l] (f16) from v[l][b][d] (f32). 32x32 LDS tiles.
// ---------------------------------------------------------------------------
__global__ __launch_bounds__(256) void vt_k(
    const float* __restrict__ v, __fp16* __restrict__ VT)
{
  __shared__ float Ts[32][33];
  const int t = threadIdx.x;
  const int d0 = blockIdx.x * 32, l0 = blockIdx.y * 32, b = blockIdx.z;
  {
    int lrow = t >> 3, dq = t & 7;
    float4 a = *(const float4*)&v[((size_t)(l0 + lrow) * 32 + b) * 256 + d0 + dq * 4];
    Ts[dq * 4 + 0][lrow] = a.x; Ts[dq * 4 + 1][lrow] = a.y;
    Ts[dq * 4 + 2][lrow] = a.z; Ts[dq * 4 + 3][lrow] = a.w;
  }
  __syncthreads();
  {
    int drow = t >> 3, lq = t & 7;
    f16x4_t o;
#pragma unroll
    for (int e = 0; e < 4; ++e) o[e] = (__fp16)Ts[drow][lq * 4 + e];
    *(f16x4_t*)&VT[((size_t)b * 256 + d0 + drow) * 512 + l0 + lq * 4] = o;
  }
}

// ---------------------------------------------------------------------------
// Packed-f16 score: S[b][i][l] = -2 * sum_h V[b][h] * rcp(1 + Eq*Ev).
// ---------------------------------------------------------------------------
__global__ __launch_bounds__(256) void score_k(
    const __fp16* __restrict__ Eq, const __fp16* __restrict__ Ev,
    const float* __restrict__ Vvec, float* __restrict__ S)
{
  __shared__ __align__(16) __fp16 Eqs[64][72];
  __shared__ __align__(16) __fp16 Evs[32][72];
  __shared__ __align__(16) __fp16 Vs[256];
  const int t = threadIdx.x;
  const int tx = t & 15, ty = t >> 4;
  const int l0 = blockIdx.x * 32;
  const int i0 = blockIdx.y * 64;
  const int b  = blockIdx.z;

  Vs[t] = (__fp16)(-2.0f * Vvec[b * 256 + t]);
  float acc[4][2] = {};
  const f16x2 one2 = {(__fp16)1.f, (__fp16)1.f};

  for (int st = 0; st < 4; ++st) {
    const int h0 = st * 64;
#pragma unroll
    for (int s = 0; s < 2; ++s) {
      int f = t + s * 256;
      int row = f >> 3, cq = f & 7;
      *(f16x8*)&Eqs[row][cq * 8] =
          *(const f16x8*)&Eq[((size_t)(i0 + row) * 32 + b) * 256 + h0 + cq * 8];
    }
    {
      int row = t >> 3, cq = t & 7;
      *(f16x8*)&Evs[row][cq * 8] =
          *(const f16x8*)&Ev[((size_t)(l0 + row) * 32 + b) * 256 + h0 + cq * 8];
    }
    __syncthreads();

#pragma unroll
    for (int k8 = 0; k8 < 8; ++k8) {
      f16x8 vh8 = *(const f16x8*)&Vs[h0 + k8 * 8];
      f16x8 ev80 = *(const f16x8*)&Evs[tx][k8 * 8];
      f16x8 ev81 = *(const f16x8*)&Evs[tx + 16][k8 * 8];
      f16x8 eq8[4];
#pragma unroll
      for (int r = 0; r < 4; ++r)
        eq8[r] = *(const f16x8*)&Eqs[ty * 4 + r][k8 * 8];
#pragma unroll
      for (int q = 0; q < 4; ++q) {
        f16x2 vh2 = {vh8[q * 2], vh8[q * 2 + 1]};
        f16x2 e0  = {ev80[q * 2], ev80[q * 2 + 1]};
        f16x2 e1  = {ev81[q * 2], ev81[q * 2 + 1]};
#pragma unroll
        for (int r = 0; r < 4; ++r) {
          f16x2 eq2 = {eq8[r][q * 2], eq8[r][q * 2 + 1]};
          f16x2 d0 = eq2 * e0 + one2;   // v_pk_fma_f16
          f16x2 d1 = eq2 * e1 + one2;
          f16x2 r0 = {rcph(d0[0]), rcph(d0[1])};
          f16x2 r1 = {rcph(d1[0]), rcph(d1[1])};
          acc[r][0] = dot2f(vh2, r0, acc[r][0]);
          acc[r][1] = dot2f(vh2, r1, acc[r][1]);
        }
      }
    }
    __syncthreads();
  }

#pragma unroll
  for (int r = 0; r < 4; ++r) {
    float* ps = &S[((size_t)b * 512 + i0 + ty * 4 + r) * 512 + l0];
    ps[tx]      = acc[r][0];
    ps[tx + 16] = acc[r][1];
  }
}

// ---------------------------------------------------------------------------
// FUSED softmax + context: C[i][b][d] = sum_l softmax_l(S[b][i][:])[l] * VT[b][d][l].
// ---------------------------------------------------------------------------
__global__ __launch_bounds__(512) void ctxsm_k(
    const float* __restrict__ S, const __fp16* __restrict__ VT,
    float* __restrict__ C)
{
  __shared__ __align__(16) __fp16 As[64][40];
  __shared__ __align__(16) __fp16 Vs[256][40];
  __shared__ float red[64][8];
  __shared__ float stat_m[64], stat_inv[64];
  const int t = threadIdx.x, wave = t >> 6, lane = t & 63;
  const int quad = lane >> 4, col = lane & 15;
  const int i0 = blockIdx.x * 64, b = blockIdx.y;
  const int mt = wave & 3, nh = wave >> 2;

  // ---- phase 1: row stats ----
  {
    const int row = t >> 3, seg = t & 7;
    const float* sp = &S[((size_t)b * 512 + i0 + row) * 512 + seg * 64];
    float m = -1e30f;
#pragma unroll
    for (int u = 0; u < 16; ++u) {
      float4 x = *(const float4*)&sp[u * 4];
      m = fmaxf(m, fmaxf(fmaxf(x.x, x.y), fmaxf(x.z, x.w)));
    }
    red[row][seg] = m;
    __syncthreads();
    if (seg == 0) {
      float mm = red[row][0];
#pragma unroll
      for (int u = 1; u < 8; ++u) mm = fmaxf(mm, red[row][u]);
      stat_m[row] = mm;
    }
    __syncthreads();
    float M = stat_m[row];
    float s = 0.f;
#pragma unroll
    for (int u = 0; u < 16; ++u) {
      float4 x = *(const float4*)&sp[u * 4];
      s += exp2_f(LOG2E * (x.x - M)) + exp2_f(LOG2E * (x.y - M)) +
           exp2_f(LOG2E * (x.z - M)) + exp2_f(LOG2E * (x.w - M));
    }
    red[row][seg] = s;
    __syncthreads();
    if (seg == 0) {
      float ss = red[row][0];
#pragma unroll
      for (int u = 1; u < 8; ++u) ss += red[row][u];
      stat_inv[row] = rcp_f(ss);
    }
    __syncthreads();
  }

  // ---- phase 2: MFMA with softmax applied at A staging ----
  f32x4 acc[8];
#pragma unroll
  for (int n = 0; n < 8; ++n) acc[n] = (f32x4){0.f, 0.f, 0.f, 0.f};

  for (int kc = 0; kc < 16; ++kc) {
    const int l0 = kc * 32;
    {
      int arow = t >> 3, aq = t & 7;
      float M = stat_m[arow], inv = stat_inv[arow];
      float4 x = *(const float4*)&S[((size_t)b * 512 + i0 + arow) * 512 + l0 + aq * 4];
      f16x4_t o;
      o[0] = (__fp16)(exp2_f(LOG2E * (x.x - M)) * inv);
      o[1] = (__fp16)(exp2_f(LOG2E * (x.y - M)) * inv);
      o[2] = (__fp16)(exp2_f(LOG2E * (x.z - M)) * inv);
      o[3] = (__fp16)(exp2_f(LOG2E * (x.w - M)) * inv);
      *(f16x4_t*)&As[arow][aq * 4] = o;
#pragma unroll
      for (int s2 = 0; s2 < 2; ++s2) {
        int f = t + s2 * 512;
        int vrow = f >> 2, vq = f & 3;
        *(f16x8*)&Vs[vrow][vq * 8] =
            *(const f16x8*)&VT[((size_t)b * 256 + vrow) * 512 + l0 + vq * 8];
      }
    }
    __syncthreads();
    f16x8 a = *(const f16x8*)&As[mt * 16 + col][quad * 8];
#pragma unroll
    for (int n = 0; n < 8; ++n) {
      f16x8 vf = *(const f16x8*)&Vs[nh * 128 + n * 16 + col][quad * 8];
      acc[n] = __builtin_amdgcn_mfma_f32_16x16x32_f16(a, vf, acc[n], 0, 0, 0);
    }
    __syncthreads();
  }

#pragma unroll
  for (int n = 0; n < 8; ++n)
#pragma unroll
    for (int r = 0; r < 4; ++r) {
      size_t i = i0 + mt * 16 + quad * 4 + r;
      size_t d = nh * 128 + n * 16 + col;
      C[(i * 32 + b) * 256 + d] = acc[n][r];
    }
}

// ---------------------------------------------------------------------------
// Gi2 = f16( C @ Wih^T + bih (+bhh for gates r,z) ). M=16384, N=768, K=256.
// ---------------------------------------------------------------------------
__global__ __launch_bounds__(256) void gi_k(
    const float* __restrict__ A, const float* __restrict__ W,
    const float* __restrict__ bih, const float* __restrict__ bhh,
    __fp16* __restrict__ G)
{
  __shared__ __align__(16) __fp16 As[64][40];
  __shared__ __align__(16) __fp16 Ws[64][40];
  const int t = threadIdx.x, wave = t >> 6, lane = t & 63;
  const int quad = lane >> 4, col = lane & 15;
  const int n0 = blockIdx.x * 64, m0 = blockIdx.y * 64;
  const int srow = t >> 2, skq = t & 3;

  f32x4 acc[4];
#pragma unroll
  for (int nt = 0; nt < 4; ++nt) acc[nt] = (f32x4){0.f, 0.f, 0.f, 0.f};

  for (int kc = 0; kc < 8; ++kc) {
    const int k0 = kc * 32;
    {
      const float4* ap = (const float4*)&A[(size_t)(m0 + srow) * 256 + k0 + skq * 8];
      *(f16x8*)&As[srow][skq * 8] = cvt8(ap[0], ap[1]);
      const float4* wp = (const float4*)&W[(size_t)(n0 + srow) * 256 + k0 + skq * 8];
      *(f16x8*)&Ws[srow][skq * 8] = cvt8(wp[0], wp[1]);
    }
    __syncthreads();
    f16x8 a = *(const f16x8*)&As[wave * 16 + col][quad * 8];
#pragma unroll
    for (int nt = 0; nt < 4; ++nt) {
      f16x8 b = *(const f16x8*)&Ws[nt * 16 + col][quad * 8];
      acc[nt] = __builtin_amdgcn_mfma_f32_16x16x32_f16(a, b, acc[nt], 0, 0, 0);
    }
    __syncthreads();
  }

#pragma unroll
  for (int nt = 0; nt < 4; ++nt) {
    int n = n0 + nt * 16 + col;
    float bias = bih[n] + (n < 512 ? bhh[n] : 0.f);
#pragma unroll
    for (int r = 0; r < 4; ++r) {
      size_t m = m0 + wave * 16 + quad * 4 + r;
      G[m * 768 + n] = (__fp16)(acc[nt][r] + bias);
    }
  }
}

// ---------------------------------------------------------------------------
// R5: dot2 GRU re-partitioned to fit the GRANTED 128-VGPR budget.
// R4 failed because 192 weight VGPRs/lane + working set > the allocator's
// 128 cap (VGPR_Count=128 + 824us = spill/remat every iteration).
// New shape: 1024 threads/block; 4-lane group per j (q = t&3 = k-quarter).
// Lane holds quarter k in [64q,64q+64) of ALL THREE gate rows:
//   96 f16x2 = 96 VGPRs (+~30 working <= 128).
// 96 dot2/lane/iter (issue floor 768 cyc/iter/CU across 16 waves).
// Quad butterfly (__shfl_xor 1,2 -> DPP quad_perm, pure VALU) gives every
// lane the full r/z/n sums -> gate math quad-local, NO LDS exchange,
// ONE lgkm-only barrier per iteration.
// h quarters stored at 80-half stride (bank groups 0/8/16/24) ->
// conflict-free 4-address broadcast ds_read_b128.
// ---------------------------------------------------------------------------
__global__ __launch_bounds__(1024, 1) void gru_k(
    const __fp16* __restrict__ Gi2, const float* __restrict__ Whh,
    const float* __restrict__ bhh, const float* __restrict__ h0,
    float* __restrict__ out)
{
  __shared__ __align__(16) __fp16 hA[2][320];   // 4 quarters x (64 + 16 pad)
  const int t = threadIdx.x;
  const int j = t >> 2, q = t & 3;
  const int b = blockIdx.x;
  const int k0 = q * 64;

  // ---- stage this lane's weight quarters (static indices only) ----
  f16x2 Wr_[32], Wz_[32], Wn_[32];
  {
    const float* r0 = &Whh[(size_t)(0   + j) * 256 + k0];
    const float* z0 = &Whh[(size_t)(256 + j) * 256 + k0];
    const float* n0 = &Whh[(size_t)(512 + j) * 256 + k0];
#pragma unroll
    for (int u = 0; u < 16; ++u) {
      float4 x = *(const float4*)&r0[u * 4];
      Wr_[u * 2 + 0] = (f16x2){(__fp16)x.x, (__fp16)x.y};
      Wr_[u * 2 + 1] = (f16x2){(__fp16)x.z, (__fp16)x.w};
      float4 y = *(const float4*)&z0[u * 4];
      Wz_[u * 2 + 0] = (f16x2){(__fp16)y.x, (__fp16)y.y};
      Wz_[u * 2 + 1] = (f16x2){(__fp16)y.z, (__fp16)y.w};
      float4 z = *(const float4*)&n0[u * 4];
      Wn_[u * 2 + 0] = (f16x2){(__fp16)z.x, (__fp16)z.y};
      Wn_[u * 2 + 1] = (f16x2){(__fp16)z.z, (__fp16)z.w};
    }
  }

  const float bn = bhh[512 + j];
  float hold = h0[(size_t)b * 256 + j];          // redundant across the quad
  const int wslot = (j >> 6) * 80 + (j & 63);    // h slot in padded layout
  if (q == 0) hA[0][wslot] = (__fp16)hold;
  __syncthreads();

  // Gi2[(i*32+b)*768 + g*256 + j]; row stride 24576 halfs.
  const __fp16* gp = &Gi2[(size_t)b * 768 + j];
  float gr = (float)gp[0], gz = (float)gp[256], gn = (float)gp[512];
  const __fp16* gq = gp + 24576;                 // row i=1

  float* outp = &out[(size_t)b * 256 + j];

  for (int i = 0; i < 512; ++i) {
    // prefetch next Gi2 row (i=511 reads one dead row; in-workspace)
    float nr = (float)gq[0], nz = (float)gq[256], nn2 = (float)gq[512];
    gq += 24576;

    // ---- dot phase: this lane's k-quarter of h ----
    const __fp16* hb = &hA[i & 1][q * 80];
    float ar0 = 0.f, ar1 = 0.f, az0 = 0.f, az1 = 0.f, an0 = 0.f, an1 = 0.f;
#pragma unroll
    for (int c = 0; c < 8; ++c) {
      f16x8 hc = *(const f16x8*)&hb[c * 8];
      f16x2 h0c = __builtin_shufflevector(hc, hc, 0, 1);
      f16x2 h1c = __builtin_shufflevector(hc, hc, 2, 3);
      f16x2 h2c = __builtin_shufflevector(hc, hc, 4, 5);
      f16x2 h3c = __builtin_shufflevector(hc, hc, 6, 7);
      ar0 = dot2f(h0c, Wr_[c * 4 + 0], ar0);
      ar1 = dot2f(h1c, Wr_[c * 4 + 1], ar1);
      ar0 = dot2f(h2c, Wr_[c * 4 + 2], ar0);
      ar1 = dot2f(h3c, Wr_[c * 4 + 3], ar1);
      az0 = dot2f(h0c, Wz_[c * 4 + 0], az0);
      az1 = dot2f(h1c, Wz_[c * 4 + 1], az1);
      az0 = dot2f(h2c, Wz_[c * 4 + 2], az0);
      az1 = dot2f(h3c, Wz_[c * 4 + 3], az1);
      an0 = dot2f(h0c, Wn_[c * 4 + 0], an0);
      an1 = dot2f(h1c, Wn_[c * 4 + 1], an1);
      an0 = dot2f(h2c, Wn_[c * 4 + 2], an0);
      an1 = dot2f(h3c, Wn_[c * 4 + 3], an1);
    }
    float ar = ar0 + ar1, az = az0 + az1, an = an0 + an1;
    // quad butterfly: DPP quad_perm, all 4 lanes end with the full sums
    ar += __shfl_xor(ar, 1); ar += __shfl_xor(ar, 2);
    az += __shfl_xor(az, 1); az += __shfl_xor(az, 2);
    an += __shfl_xor(an, 1); an += __shfl_xor(an, 2);

    // ---- gates (redundant across the quad; no divergence) ----
    float rr = rcp_f(1.f + exp2_f(-LOG2E * (gr + ar)));
    float zz = rcp_f(1.f + exp2_f(-LOG2E * (gz + az)));
    float na = fmaf(rr, an + bn, gn);
    float nn = fmaf(-2.f, rcp_f(1.f + exp2_f(C2 * na)), 1.f);
    float h  = fmaf(zz, hold - nn, nn);
    hold = h;
    if (q == 0) {
      outp[0] = h;
      hA[(i + 1) & 1][wslot] = (__fp16)h;
    }
    outp += 8192;
    gr = nr; gz = nz; gn = nn2;

    // one barrier per iter: order the h hand-off only (lgkm drain; out
    // stores and gi prefetch loads stay in flight on vmcnt).
    asm volatile("s_waitcnt lgkmcnt(0)" ::: "memory");
    __builtin_amdgcn_s_barrier();
    asm volatile("" ::: "memory");
  }
}

// ---------------------------------------------------------------------------
extern "C" void kernel_launch(void* const* d_in, const int* in_sizes, int n_in,
                              void* d_out, int out_size, void* d_ws, size_t ws_size,
                              hipStream_t stream)
{
  const float* v   = (const float*)d_in[0];
  const float* h0  = (const float*)d_in[1];
  const float* Vv  = (const float*)d_in[2];
  const float* Wp  = (const float*)d_in[3];
  const float* Wp_ = (const float*)d_in[4];
  const float* Wih = (const float*)d_in[5];
  const float* Whh = (const float*)d_in[6];
  const float* bih = (const float*)d_in[7];
  const float* bhh = (const float*)d_in[8];
  float* out = (float*)d_out;
  float* ws  = (float*)d_ws;

  __fp16* Eq  = (__fp16*)ws;
  __fp16* Ev  = (__fp16*)(ws + 2097152);
  __fp16* VT  = (__fp16*)(ws + 4194304);
  float*  S   = ws + 6291456;
  float*  C   = ws;                        // reuse Eq+Ev (dead after score)
  __fp16* Gi2 = (__fp16*)(ws + 6291456);   // reuse S (dead after ctxsm)

  proj_k<<<dim3(4, 256), 256, 0, stream>>>(v, Wp, Wp_, Eq, Ev);
  vt_k<<<dim3(8, 16, 32), 256, 0, stream>>>(v, VT);
  score_k<<<dim3(16, 8, 32), 256, 0, stream>>>(Eq, Ev, Vv, S);
  ctxsm_k<<<dim3(8, 32), 512, 0, stream>>>(S, VT, C);
  gi_k<<<dim3(12, 256), 256, 0, stream>>>(C, Wih, bih, bhh, Gi2);
  gru_k<<<32, 1024, 0, stream>>>(Gi2, Whh, bhh, h0, out);
}